// Round 4
// baseline (409.147 us; speedup 1.0000x reference)
//
#include <hip/hip_runtime.h>
#include <hip/hip_bf16.h>

typedef __attribute__((ext_vector_type(4))) float f32x4;
typedef __attribute__((ext_vector_type(8))) short bf16x8;

#define NEG_L2K (-0.025952563241307517f)  // -log2(10000)/512

#define VMW(N) asm volatile("s_waitcnt vmcnt(" #N ")" ::: "memory")
#define SCHB() __builtin_amdgcn_sched_barrier(0)
#define SBAR() __builtin_amdgcn_s_barrier()

__device__ __forceinline__ unsigned short f2bf(float f) {
    union { float f; unsigned int u; } v; v.f = f;
    unsigned int r = v.u + 0x7FFFu + ((v.u >> 16) & 1u);
    return (unsigned short)(r >> 16);
}

__device__ __forceinline__ f32x4 MFMA(bf16x8 a, bf16x8 b, f32x4 c) {
    return __builtin_amdgcn_mfma_f32_16x16x32_bf16(a, b, c, 0, 0, 0);
}

// async global->VGPR 16B load; program order pinned by volatile+memory so the
// manual vmcnt ledger stays valid.  Consumed only after the matching VMW.
__device__ __forceinline__ bf16x8 gload16(const unsigned short* p) {
    bf16x8 r;
    asm volatile("global_load_dwordx4 %0, %1, off" : "=v"(r) : "v"(p) : "memory");
    return r;
}

// ---------------- Kernel 1: X fp32 -> bf16 (same layout); zero A[8192] ----
__global__ void prep_x_kernel(const float* __restrict__ X,
                              unsigned short* __restrict__ Xb,
                              float* __restrict__ A, int n8) {
    int gid = blockIdx.x * blockDim.x + threadIdx.x;
    if (gid < 8192) A[gid] = 0.0f;
    int stride = gridDim.x * blockDim.x;
    for (int i = gid; i < n8; i += stride) {
        float4 a = ((const float4*)X)[2 * i];
        float4 b = ((const float4*)X)[2 * i + 1];
        union { unsigned short us[8]; uint4 v; } o;
        o.us[0] = f2bf(a.x); o.us[1] = f2bf(a.y);
        o.us[2] = f2bf(a.z); o.us[3] = f2bf(a.w);
        o.us[4] = f2bf(b.x); o.us[5] = f2bf(b.y);
        o.us[6] = f2bf(b.z); o.us[7] = f2bf(b.w);
        ((uint4*)Xb)[i] = o.v;
    }
}

// ---------------- Kernel 2: W [2048][4096] fp32 -> Wt [4096][2048] bf16 ---
__global__ __launch_bounds__(256) void prep_w_kernel(const float* __restrict__ W,
                                                     unsigned short* __restrict__ Wt) {
    __shared__ unsigned short t[64][65];
    int f0 = blockIdx.x * 64;   // along 4096
    int k0 = blockIdx.y * 64;   // along 2048
    int tx = threadIdx.x & 63;
    int ty = threadIdx.x >> 6;  // 0..3
    for (int j = 0; j < 64; j += 4)
        t[ty + j][tx] = f2bf(W[(size_t)(k0 + ty + j) * 4096 + f0 + tx]);
    __syncthreads();
    for (int j = 0; j < 64; j += 4)
        Wt[(size_t)(f0 + ty + j) * 2048 + k0 + tx] = t[tx][ty + j];
}

// ---- staging helper: one 128-row x 64-col bf16 tile (16 KB), 2 loads/thread
// LDS dest linear; global source pre-swizzled (chunk jl = jp ^ (row&7)) so the
// swizzled ds_reads (T2) see the right data.
__device__ __forceinline__ void stage128(const unsigned short* __restrict__ g,
                                         unsigned short* lds, int tid) {
    int lane = tid & 63, w = tid >> 6;
    #pragma unroll
    for (int q = 0; q < 2; ++q) {
        int c = (q * 8 + w) * 64 + lane;          // physical 16B-chunk id
        int row = c >> 3;
        int jl = (c & 7) ^ (row & 7);             // logical chunk in row
        __builtin_amdgcn_global_load_lds(
            (const __attribute__((address_space(1))) void*)(g + (size_t)row * 2048 + jl * 8),
            (__attribute__((address_space(3))) void*)(lds + c * 8), 16, 0, 0);
    }
}

// ---------------- Kernel 3: fused GEMM + rotary + cos*cos + col-reduce ----
// A staged in LDS (T2-swizzled, dbuf 64 KiB); B (K,V cols) global->reg dbuf.
// Ledger/K-step: issue [Alo2,BK4] in P0, [Ahi2,BV4] in P1; waits VMW(4),VMW(6).
__global__ __launch_bounds__(512, 2) void gemm_acos_kernel(
    const unsigned short* __restrict__ Xb,   // [16384][2048]
    const unsigned short* __restrict__ Wt,   // [4096][2048]
    const float* __restrict__ bias,          // [4096]
    float* __restrict__ A)                   // [4][2048]
{
    __shared__ __align__(16) unsigned short Als[2][256 * 64];  // 64 KB

    const int tid  = threadIdx.x;
    const int lane = tid & 63;
    const int wid  = tid >> 6;    // 0..7
    const int wr   = wid >> 2;    // 0..1  (row half: 128 rows)
    const int wc   = wid & 3;     // 0..3  (col quarter: 32 cols)
    const int lr   = lane & 15;
    const int hi   = lane >> 4;   // 0..3
    const int e    = lane & 7;

    // T1: bijective XCD swizzle, grid 1024 = 64 mtiles x 16 ntiles, ntile-major
    const int orig  = blockIdx.x;
    const int wg    = (orig & 7) * 128 + (orig >> 3);
    const int mtile = wg & 63;
    const int ntile = wg >> 6;
    const int row0  = mtile * 256;
    const int n0    = ntile * 128;

    const unsigned short* gA  = Xb + (size_t)row0 * 2048;
    const unsigned short* gKb = Wt + (size_t)(n0 + wc * 32 + lr) * 2048 + hi * 8;
    const unsigned short* gVb = gKb + (size_t)2048 * 2048;

    f32x4 accK[4][2][2] = {};   // [m-frag-within-half? no: m 0..3][n][half via sep arrays]
    f32x4 accK2[4][2] = {};
    f32x4 accV1[4][2] = {};
    f32x4 accV2[4][2] = {};
    f32x4 accK1[4][2] = {};
    (void)accK;

    // ds_read byte offsets (T2-swizzled chunk: (ks*4+hi) ^ e), e == rowread&7
    const int aoff = (wr * 128 + lr) * 128;
    const int x0   = ((0 + hi) ^ e) * 16;
    const int x1   = ((4 + hi) ^ e) * 16;

    bf16x8 bkA[2][2], bvA[2][2], bkB[2][2], bvB[2][2];

    // prologue: queue = [Alo(0):2, BK(0):4, Ahi(0):2, BV(0):4]
    stage128(gA, Als[0], tid);
    #pragma unroll
    for (int n = 0; n < 2; ++n) {
        bkA[n][0] = gload16(gKb + n * 16 * 2048 + 0);
        bkA[n][1] = gload16(gKb + n * 16 * 2048 + 32);
    }
    stage128(gA + 128 * 2048, Als[0] + 128 * 64, tid);
    #pragma unroll
    for (int n = 0; n < 2; ++n) {
        bvA[n][0] = gload16(gVb + n * 16 * 2048 + 0);
        bvA[n][1] = gload16(gVb + n * 16 * 2048 + 32);
    }

    int kt = 0;
    #pragma unroll 1
    for (int it = 0; it < 16; ++it) {
        #pragma unroll
        for (int sub = 0; sub < 2; ++sub) {
            const int cur = sub;                      // buffer parity == sub
            const char* As = (const char*)Als[cur];
            unsigned short* An = Als[cur ^ 1];
            const int ktn = (kt + 64) & 2047;         // wraps harmlessly at end
            bf16x8 (&bkC)[2][2] = sub ? bkB : bkA;    // current (static index)
            bf16x8 (&bvC)[2][2] = sub ? bvB : bvA;
            bf16x8 (&bkN)[2][2] = sub ? bkA : bkB;    // next
            bf16x8 (&bvN)[2][2] = sub ? bvA : bvB;

            bf16x8 af0[4][2], af1[4][2];

            // ---- P0: wait A(t)+BK(t)  [leave BV(t):4 in flight]
            VMW(4); SCHB();
            SBAR();
            #pragma unroll
            for (int m = 0; m < 4; ++m) {
                af0[m][0] = *(const bf16x8*)(As + aoff + m * 2048 + x0);
                af0[m][1] = *(const bf16x8*)(As + aoff + m * 2048 + x1);
            }
            stage128(gA + ktn, An, tid);
            #pragma unroll
            for (int n = 0; n < 2; ++n) {
                bkN[n][0] = gload16(gKb + n * 16 * 2048 + ktn);
                bkN[n][1] = gload16(gKb + n * 16 * 2048 + ktn + 32);
            }
            SBAR();
            __builtin_amdgcn_s_setprio(1);
            #pragma unroll
            for (int m = 0; m < 4; ++m)
                #pragma unroll
                for (int n = 0; n < 2; ++n) {
                    accK1[m][n] = MFMA(af0[m][0], bkC[n][0], accK1[m][n]);
                    accK1[m][n] = MFMA(af0[m][1], bkC[n][1], accK1[m][n]);
                }
            __builtin_amdgcn_s_setprio(0);

            // ---- P1: wait BV(t)  [leave Alo(t+1)+BK(t+1):6]
            VMW(6); SCHB();
            SBAR();
            stage128(gA + 128 * 2048 + ktn, An + 128 * 64, tid);
            #pragma unroll
            for (int n = 0; n < 2; ++n) {
                bvN[n][0] = gload16(gVb + n * 16 * 2048 + ktn);
                bvN[n][1] = gload16(gVb + n * 16 * 2048 + ktn + 32);
            }
            SBAR();
            __builtin_amdgcn_s_setprio(1);
            #pragma unroll
            for (int m = 0; m < 4; ++m)
                #pragma unroll
                for (int n = 0; n < 2; ++n) {
                    accV1[m][n] = MFMA(af0[m][0], bvC[n][0], accV1[m][n]);
                    accV1[m][n] = MFMA(af0[m][1], bvC[n][1], accV1[m][n]);
                }
            __builtin_amdgcn_s_setprio(0);

            // ---- P2/P3: pure-MFMA tail on rows m+4 (no barriers needed:
            // buffer stays valid; next overwrite issue is after P0(t+1) SBAR)
            #pragma unroll
            for (int m = 0; m < 4; ++m) {
                af1[m][0] = *(const bf16x8*)(As + aoff + (m + 4) * 2048 + x0);
                af1[m][1] = *(const bf16x8*)(As + aoff + (m + 4) * 2048 + x1);
            }
            __builtin_amdgcn_s_setprio(1);
            #pragma unroll
            for (int m = 0; m < 4; ++m)
                #pragma unroll
                for (int n = 0; n < 2; ++n) {
                    accK2[m][n] = MFMA(af1[m][0], bkC[n][0], accK2[m][n]);
                    accK2[m][n] = MFMA(af1[m][1], bkC[n][1], accK2[m][n]);
                }
            #pragma unroll
            for (int m = 0; m < 4; ++m)
                #pragma unroll
                for (int n = 0; n < 2; ++n) {
                    accV2[m][n] = MFMA(af1[m][0], bvC[n][0], accV2[m][n]);
                    accV2[m][n] = MFMA(af1[m][1], bvC[n][1], accV2[m][n]);
                }
            __builtin_amdgcn_s_setprio(0);

            kt += 64;
        }
    }
    VMW(0);   // drain stray prefetches before LDS is handed to the next block

    // ---- epilogue: bias, rotary, cos*cos, reduce over rows, atomicAdd
    const int batch = row0 >> 12;
    const int sbase = (row0 & 4095) + wr * 128 + hi * 4;

    #pragma unroll
    for (int n = 0; n < 2; ++n) {
        const int c     = n0 + wc * 32 + n * 16 + lr;   // channel in [0,2048)
        const float bK  = bias[c];
        const float bV  = bias[c + 2048];
        const bool rot  = (c < 1024);
        const float invf = exp2f((float)(c >> 1) * NEG_L2K);
        const float sgn  = (c & 1) ? 1.0f : -1.0f;
        float colsum = 0.0f;
        #pragma unroll
        for (int m = 0; m < 8; ++m) {
            const int srow = sbase + (m & 3) * 16 + (m >> 2) * 64;
            const f32x4 aK = (m < 4) ? accK1[m & 3][n] : accK2[m & 3][n];
            const f32x4 aV = (m < 4) ? accV1[m & 3][n] : accV2[m & 3][n];
            #pragma unroll
            for (int q = 0; q < 4; ++q) {
                float kv = aK[q] + bK;
                float vv = aV[q] + bV;
                float pk = __shfl_xor(kv, 1);
                float pv = __shfl_xor(vv, 1);
                float kr = kv, vr = vv;
                if (rot) {
                    float sn, cs;
                    __sincosf((float)(srow + q) * invf, &sn, &cs);
                    float tt = sgn * sn;
                    kr = kv * cs + pk * tt;
                    vr = vv * cs + pv * tt;
                }
                colsum += __cosf(kr) * __cosf(vr);
            }
        }
        colsum += __shfl_xor(colsum, 16);
        colsum += __shfl_xor(colsum, 32);
        if (lane < 16)
            atomicAdd(&A[batch * 2048 + c], colsum);
    }
}

// ---------------- Kernel 4: out = (0.5*A + 0.5) * X --------------------
__global__ void scale_out_kernel(const float* __restrict__ X,
                                 const float* __restrict__ A,
                                 float* __restrict__ out, int n4) {
    int gid = blockIdx.x * blockDim.x + threadIdx.x;
    int stride = gridDim.x * blockDim.x;
    for (int i = gid; i < n4; i += stride) {
        int e0 = i * 4;
        int b  = e0 >> 23;        // S*D = 2^23
        int d  = e0 & 2047;
        float4 a4 = *(const float4*)(A + b * 2048 + d);
        float4 x4 = ((const float4*)X)[i];
        float4 o;
        o.x = (0.5f * a4.x + 0.5f) * x4.x;
        o.y = (0.5f * a4.y + 0.5f) * x4.y;
        o.z = (0.5f * a4.z + 0.5f) * x4.z;
        o.w = (0.5f * a4.w + 0.5f) * x4.w;
        ((float4*)out)[i] = o;
    }
}

extern "C" void kernel_launch(void* const* d_in, const int* in_sizes, int n_in,
                              void* d_out, int out_size, void* d_ws, size_t ws_size,
                              hipStream_t stream) {
    const float* X    = (const float*)d_in[0];   // [4][4096][2048]
    const float* W    = (const float*)d_in[1];   // [2048][4096]
    const float* bias = (const float*)d_in[2];   // [4096]
    float* out = (float*)d_out;

    const size_t szA  = 32768;                       // 4*2048*4 (padded)
    const size_t szWt = (size_t)4096 * 2048 * 2;     // 16.8 MB
    const size_t szXb = (size_t)16384 * 2048 * 2;    // 67.1 MB

    char* ws = (char*)d_ws;
    float* A = (float*)ws;                           // assume ws >= 32 KB
    unsigned short* Wt;
    unsigned short* Xb;
    if (ws_size >= szA + szWt + szXb) {
        Wt = (unsigned short*)(ws + szA);
        Xb = (unsigned short*)(ws + szA + szWt);
    } else if (ws_size >= szA + szWt) {
        Wt = (unsigned short*)(ws + szA);
        Xb = (unsigned short*)d_out;                 // scratch; rewritten by kernel 4
    } else {
        Xb = (unsigned short*)d_out;
        Wt = (unsigned short*)((char*)d_out + szXb); // 67+16.8 MB <= 134 MB
    }

    prep_x_kernel<<<2048, 256, 0, stream>>>(X, Xb, A, 16384 * 2048 / 8);
    prep_w_kernel<<<dim3(64, 32), 256, 0, stream>>>(W, Wt);
    gemm_acos_kernel<<<1024, 512, 0, stream>>>(Xb, Wt, bias, A);
    scale_out_kernel<<<2048, 256, 0, stream>>>(X, A, out, 16384 * 2048 / 4);
}

// Round 5
// 328.148 us; speedup vs baseline: 1.2468x; 1.2468x over previous
//
#include <hip/hip_runtime.h>
#include <hip/hip_bf16.h>

typedef __attribute__((ext_vector_type(4))) float f32x4;
typedef __attribute__((ext_vector_type(8))) short bf16x8;

#define NEG_L2K (-0.025952563241307517f)  // -log2(10000)/512

#define VMW(N) asm volatile("s_waitcnt vmcnt(" #N ")" ::: "memory")
#define SCHB() __builtin_amdgcn_sched_barrier(0)
#define SBAR() __builtin_amdgcn_s_barrier()

__device__ __forceinline__ unsigned short f2bf(float f) {
    union { float f; unsigned int u; } v; v.f = f;
    unsigned int r = v.u + 0x7FFFu + ((v.u >> 16) & 1u);
    return (unsigned short)(r >> 16);
}

__device__ __forceinline__ f32x4 MFMA(bf16x8 a, bf16x8 b, f32x4 c) {
    return __builtin_amdgcn_mfma_f32_16x16x32_bf16(a, b, c, 0, 0, 0);
}

// ---------------- Kernel 1: X fp32 -> bf16 (same layout); zero A[8192] ----
__global__ void prep_x_kernel(const float* __restrict__ X,
                              unsigned short* __restrict__ Xb,
                              float* __restrict__ A, int n8) {
    int gid = blockIdx.x * blockDim.x + threadIdx.x;
    if (gid < 8192) A[gid] = 0.0f;
    int stride = gridDim.x * blockDim.x;
    for (int i = gid; i < n8; i += stride) {
        float4 a = ((const float4*)X)[2 * i];
        float4 b = ((const float4*)X)[2 * i + 1];
        union { unsigned short us[8]; uint4 v; } o;
        o.us[0] = f2bf(a.x); o.us[1] = f2bf(a.y);
        o.us[2] = f2bf(a.z); o.us[3] = f2bf(a.w);
        o.us[4] = f2bf(b.x); o.us[5] = f2bf(b.y);
        o.us[6] = f2bf(b.z); o.us[7] = f2bf(b.w);
        ((uint4*)Xb)[i] = o.v;
    }
}

// ---------------- Kernel 2: W [2048][4096] fp32 -> Wt [4096][2048] bf16 ---
__global__ __launch_bounds__(256) void prep_w_kernel(const float* __restrict__ W,
                                                     unsigned short* __restrict__ Wt) {
    __shared__ unsigned short t[64][65];
    int f0 = blockIdx.x * 64;   // along 4096
    int k0 = blockIdx.y * 64;   // along 2048
    int tx = threadIdx.x & 63;
    int ty = threadIdx.x >> 6;  // 0..3
    for (int j = 0; j < 64; j += 4)
        t[ty + j][tx] = f2bf(W[(size_t)(k0 + ty + j) * 4096 + f0 + tx]);
    __syncthreads();
    for (int j = 0; j < 64; j += 4)
        Wt[(size_t)(f0 + ty + j) * 2048 + k0 + tx] = t[tx][ty + j];
}

// ---- staging helper: one 128-row x 64-col bf16 tile (16 KB), 2 loads/thread
// LDS dest linear; global source pre-swizzled (chunk jl = jp ^ (row&7)) so the
// swizzled ds_reads (T2) see the right data.
__device__ __forceinline__ void stage128(const unsigned short* __restrict__ g,
                                         unsigned short* lds, int tid) {
    int lane = tid & 63, w = tid >> 6;
    #pragma unroll
    for (int q = 0; q < 2; ++q) {
        int c = (q * 8 + w) * 64 + lane;          // physical 16B-chunk id
        int row = c >> 3;
        int jl = (c & 7) ^ (row & 7);             // logical chunk in row
        __builtin_amdgcn_global_load_lds(
            (const __attribute__((address_space(1))) void*)(g + (size_t)row * 2048 + jl * 8),
            (__attribute__((address_space(3))) void*)(lds + c * 8), 16, 0, 0);
    }
}

// ---------------- Kernel 3: fused GEMM + rotary + cos*cos + col-reduce ----
// R2 structure (BM=256, BN=128+paired V, BK=64, 8 waves, dbuf 128 KiB, T1/T2/T5)
// with a deep single-wait pipeline: per K-tile, issue ALL 8 next-tile stage
// loads up front, then one counted VMW(8) + 2 barriers (vs R2's 2 waits + 8
// barriers).  Ledger: at P0 top outstanding = tile t (8); issue t+1 (16);
// VMW(8) drains exactly tile t, leaves t+1 in flight a full iteration.
__global__ __launch_bounds__(512, 2) void gemm_acos_kernel(
    const unsigned short* __restrict__ Xb,   // [16384][2048]
    const unsigned short* __restrict__ Wt,   // [4096][2048]
    const float* __restrict__ bias,          // [4096]
    float* __restrict__ A)                   // [4][2048]
{
    __shared__ __align__(16) unsigned short Als[2][256 * 64];  // 64 KB
    __shared__ __align__(16) unsigned short Kls[2][128 * 64];  // 32 KB
    __shared__ __align__(16) unsigned short Vls[2][128 * 64];  // 32 KB

    const int tid  = threadIdx.x;
    const int lane = tid & 63;
    const int wid  = tid >> 6;    // 0..7
    const int wr   = wid >> 2;    // 0..1  (row half: 128 rows)
    const int wc   = wid & 3;     // 0..3  (col quarter: 32 cols)
    const int lr   = lane & 15;
    const int hi   = lane >> 4;   // 0..3
    const int e    = lane & 7;

    // T1: bijective XCD swizzle, grid 1024 = 64 mtiles x 16 ntiles, ntile-major
    const int orig  = blockIdx.x;
    const int wg    = (orig & 7) * 128 + (orig >> 3);
    const int mtile = wg & 63;
    const int ntile = wg >> 6;
    const int row0  = mtile * 256;
    const int n0    = ntile * 128;

    const unsigned short* gA = Xb + (size_t)row0 * 2048;
    const unsigned short* gK = Wt + (size_t)n0 * 2048;
    const unsigned short* gV = Wt + (size_t)(n0 + 2048) * 2048;

    f32x4 accK[8][2] = {};
    f32x4 accV[8][2] = {};

    // ds_read byte offsets (T2-swizzled chunk: (ks*4+hi) ^ (lane&7))
    const int aoff = (wr * 128 + lr) * 128;
    const int boff = (wc * 32 + lr) * 128;
    const int x0   = ((0 + hi) ^ e) * 16;
    const int x1   = ((4 + hi) ^ e) * 16;

    // prologue: stage tile 0 into buf 0 (8 loads)
    stage128(gA,              Als[0],            tid);
    stage128(gA + 128 * 2048, Als[0] + 128 * 64, tid);
    stage128(gK,              Kls[0],            tid);
    stage128(gV,              Vls[0],            tid);

    #pragma unroll 1
    for (int it = 0; it < 16; ++it) {
        #pragma unroll
        for (int sub = 0; sub < 2; ++sub) {
            const int kt  = (it * 2 + sub) * 64;
            const bool last = (kt == 2048 - 64);
            const int cur = sub;                     // buffer parity == sub
            const char* As = (const char*)Als[cur];
            const char* Ks = (const char*)Kls[cur];
            const char* Vs = (const char*)Vls[cur];
            unsigned short* An = Als[cur ^ 1];
            unsigned short* Kn = Kls[cur ^ 1];
            unsigned short* Vn = Vls[cur ^ 1];
            const int ktn = kt + 64;

            bf16x8 af0[4][2], af1[4][2], bk[2][2], bv[2][2];

            // ---- P0: issue full next-tile prefetch, then single counted wait
            if (!last) {
                stage128(gA + ktn,              An,            tid);
                stage128(gA + 128 * 2048 + ktn, An + 128 * 64, tid);
                stage128(gK + ktn,              Kn,            tid);
                stage128(gV + ktn,              Vn,            tid);
                VMW(8);                // drain tile t; leave t+1's 8 in flight
            } else {
                VMW(0);
            }
            SCHB();
            SBAR();                    // tile t visible to all waves
            #pragma unroll
            for (int m = 0; m < 4; ++m) {
                af0[m][0] = *(const bf16x8*)(As + aoff + m * 2048 + x0);
                af0[m][1] = *(const bf16x8*)(As + aoff + m * 2048 + x1);
            }
            #pragma unroll
            for (int n = 0; n < 2; ++n) {
                bk[n][0] = *(const bf16x8*)(Ks + boff + n * 2048 + x0);
                bk[n][1] = *(const bf16x8*)(Ks + boff + n * 2048 + x1);
            }
            __builtin_amdgcn_s_setprio(1);
            #pragma unroll
            for (int m = 0; m < 4; ++m)
                #pragma unroll
                for (int n = 0; n < 2; ++n) {
                    accK[m][n] = MFMA(af0[m][0], bk[n][0], accK[m][n]);
                    accK[m][n] = MFMA(af0[m][1], bk[n][1], accK[m][n]);
                }
            __builtin_amdgcn_s_setprio(0);

            // ---- P1: V rows m0-3
            #pragma unroll
            for (int n = 0; n < 2; ++n) {
                bv[n][0] = *(const bf16x8*)(Vs + boff + n * 2048 + x0);
                bv[n][1] = *(const bf16x8*)(Vs + boff + n * 2048 + x1);
            }
            __builtin_amdgcn_s_setprio(1);
            #pragma unroll
            for (int m = 0; m < 4; ++m)
                #pragma unroll
                for (int n = 0; n < 2; ++n) {
                    accV[m][n] = MFMA(af0[m][0], bv[n][0], accV[m][n]);
                    accV[m][n] = MFMA(af0[m][1], bv[n][1], accV[m][n]);
                }
            __builtin_amdgcn_s_setprio(0);

            // ---- P2: K rows m4-7; barrier AFTER the consuming MFMAs so all
            // buf[t] ds_reads are provably landed before anyone stages t+2.
            #pragma unroll
            for (int m = 0; m < 4; ++m) {
                af1[m][0] = *(const bf16x8*)(As + aoff + (m + 4) * 2048 + x0);
                af1[m][1] = *(const bf16x8*)(As + aoff + (m + 4) * 2048 + x1);
            }
            __builtin_amdgcn_s_setprio(1);
            #pragma unroll
            for (int m = 0; m < 4; ++m)
                #pragma unroll
                for (int n = 0; n < 2; ++n) {
                    accK[m + 4][n] = MFMA(af1[m][0], bk[n][0], accK[m + 4][n]);
                    accK[m + 4][n] = MFMA(af1[m][1], bk[n][1], accK[m + 4][n]);
                }
            __builtin_amdgcn_s_setprio(0);
            SBAR();                    // all reads of buf[t] complete

            // ---- P3: pure MFMA (V rows m4-7)
            __builtin_amdgcn_s_setprio(1);
            #pragma unroll
            for (int m = 0; m < 4; ++m)
                #pragma unroll
                for (int n = 0; n < 2; ++n) {
                    accV[m + 4][n] = MFMA(af1[m][0], bv[n][0], accV[m + 4][n]);
                    accV[m + 4][n] = MFMA(af1[m][1], bv[n][1], accV[m + 4][n]);
                }
            __builtin_amdgcn_s_setprio(0);
        }
    }

    // ---- epilogue: bias, rotary, cos*cos, reduce over rows, atomicAdd
    const int batch = row0 >> 12;
    const int sb    = (row0 & 4095) + wr * 128 + hi * 4;

    #pragma unroll
    for (int n = 0; n < 2; ++n) {
        const int c     = n0 + wc * 32 + n * 16 + lr;   // channel in [0,2048)
        const float bK  = bias[c];
        const float bV  = bias[c + 2048];
        const bool rot  = (c < 1024);
        const float invf = exp2f((float)(c >> 1) * NEG_L2K);
        const float sgn  = (c & 1) ? 1.0f : -1.0f;
        float colsum = 0.0f;
        #pragma unroll
        for (int m = 0; m < 8; ++m) {
            const int srow = sb + m * 16;
            #pragma unroll
            for (int q = 0; q < 4; ++q) {
                float kv = accK[m][n][q] + bK;
                float vv = accV[m][n][q] + bV;
                float pk = __shfl_xor(kv, 1);
                float pv = __shfl_xor(vv, 1);
                float kr = kv, vr = vv;
                if (rot) {
                    float sn, cs;
                    __sincosf((float)(srow + q) * invf, &sn, &cs);
                    float tt = sgn * sn;
                    kr = kv * cs + pk * tt;
                    vr = vv * cs + pv * tt;
                }
                colsum += __cosf(kr) * __cosf(vr);
            }
        }
        colsum += __shfl_xor(colsum, 16);
        colsum += __shfl_xor(colsum, 32);
        if (lane < 16)
            atomicAdd(&A[batch * 2048 + c], colsum);
    }
}

// ---------------- Kernel 4: out = (0.5*A + 0.5) * X --------------------
__global__ void scale_out_kernel(const float* __restrict__ X,
                                 const float* __restrict__ A,
                                 float* __restrict__ out, int n4) {
    int gid = blockIdx.x * blockDim.x + threadIdx.x;
    int stride = gridDim.x * blockDim.x;
    for (int i = gid; i < n4; i += stride) {
        int e0 = i * 4;
        int b  = e0 >> 23;        // S*D = 2^23
        int d  = e0 & 2047;
        float4 a4 = *(const float4*)(A + b * 2048 + d);
        float4 x4 = ((const float4*)X)[i];
        float4 o;
        o.x = (0.5f * a4.x + 0.5f) * x4.x;
        o.y = (0.5f * a4.y + 0.5f) * x4.y;
        o.z = (0.5f * a4.z + 0.5f) * x4.z;
        o.w = (0.5f * a4.w + 0.5f) * x4.w;
        ((float4*)out)[i] = o;
    }
}

extern "C" void kernel_launch(void* const* d_in, const int* in_sizes, int n_in,
                              void* d_out, int out_size, void* d_ws, size_t ws_size,
                              hipStream_t stream) {
    const float* X    = (const float*)d_in[0];   // [4][4096][2048]
    const float* W    = (const float*)d_in[1];   // [2048][4096]
    const float* bias = (const float*)d_in[2];   // [4096]
    float* out = (float*)d_out;

    const size_t szA  = 32768;                       // 4*2048*4 (padded)
    const size_t szWt = (size_t)4096 * 2048 * 2;     // 16.8 MB
    const size_t szXb = (size_t)16384 * 2048 * 2;    // 67.1 MB

    char* ws = (char*)d_ws;
    float* A = (float*)ws;                           // assume ws >= 32 KB
    unsigned short* Wt;
    unsigned short* Xb;
    if (ws_size >= szA + szWt + szXb) {
        Wt = (unsigned short*)(ws + szA);
        Xb = (unsigned short*)(ws + szA + szWt);
    } else if (ws_size >= szA + szWt) {
        Wt = (unsigned short*)(ws + szA);
        Xb = (unsigned short*)d_out;                 // scratch; rewritten by kernel 4
    } else {
        Xb = (unsigned short*)d_out;
        Wt = (unsigned short*)((char*)d_out + szXb); // 67+16.8 MB <= 134 MB
    }

    prep_x_kernel<<<2048, 256, 0, stream>>>(X, Xb, A, 16384 * 2048 / 8);
    prep_w_kernel<<<dim3(64, 32), 256, 0, stream>>>(W, Wt);
    gemm_acos_kernel<<<1024, 512, 0, stream>>>(Xb, Wt, bias, A);
    scale_out_kernel<<<2048, 256, 0, stream>>>(X, A, out, 16384 * 2048 / 4);
}